// Round 1
// baseline (855.461 us; speedup 1.0000x reference)
//
#include <hip/hip_runtime.h>

#define HD 64
#define OD 32
#define NRELS 8
#define NB 8

__device__ __forceinline__ int rfl(int v) { return __builtin_amdgcn_readfirstlane(v); }
__device__ __forceinline__ float rflf(float v) {
    return __uint_as_float(__builtin_amdgcn_readfirstlane(__float_as_uint(v)));
}

// ---- precompute W1 = comp1 @ basis1, W2 = comp2 @ basis2 ----
__global__ void wprep_kernel(const float* __restrict__ basis1, const float* __restrict__ comp1,
                             const float* __restrict__ basis2, const float* __restrict__ comp2,
                             float* __restrict__ W1, float* __restrict__ W2) {
    int idx = blockIdx.x * blockDim.x + threadIdx.x;
    const int n1 = NRELS * HD * HD;   // 32768
    const int n2 = NRELS * HD * OD;   // 16384
    if (idx < n1) {
        int r = idx >> 12;            // / (64*64)
        int rem = idx & 4095;
        float s = 0.f;
#pragma unroll
        for (int b = 0; b < NB; ++b) s = fmaf(comp1[r * NB + b], basis1[b * HD * HD + rem], s);
        W1[idx] = s;
    } else if (idx < n1 + n2) {
        int j = idx - n1;
        int r = j >> 11;              // / (64*32)
        int rem = j & 2047;
        float s = 0.f;
#pragma unroll
        for (int b = 0; b < NB; ++b) s = fmaf(comp2[r * NB + b], basis2[b * HD * OD + rem], s);
        W2[j] = s;
    }
}

// ---- init h1 = bias1 (broadcast), out = bias2 (broadcast) ----
__global__ void init_kernel(const float* __restrict__ bias1, const float* __restrict__ bias2,
                            float* __restrict__ h1, float* __restrict__ out, int nNodes) {
    int n1 = nNodes * HD;
    int total = nNodes * (HD + OD);
    for (int idx = blockIdx.x * blockDim.x + threadIdx.x; idx < total;
         idx += gridDim.x * blockDim.x) {
        if (idx < n1) h1[idx] = bias1[idx & (HD - 1)];
        else          out[idx - n1] = bias2[(idx - n1) & (OD - 1)];
    }
}

// ---- counting sort by etype: histogram ----
__global__ void hist_kernel(const int* __restrict__ etype, int* __restrict__ relCount, int nEdges) {
    __shared__ int h[NRELS];
    if (threadIdx.x < NRELS) h[threadIdx.x] = 0;
    __syncthreads();
    for (int i = blockIdx.x * blockDim.x + threadIdx.x; i < nEdges;
         i += gridDim.x * blockDim.x)
        atomicAdd(&h[etype[i]], 1);
    __syncthreads();
    if (threadIdx.x < NRELS) atomicAdd(&relCount[threadIdx.x], h[threadIdx.x]);
}

__global__ void scan_kernel(const int* __restrict__ relCount, int* __restrict__ running) {
    if (threadIdx.x == 0 && blockIdx.x == 0) {
        int off = 0;
        for (int r = 0; r < NRELS; ++r) { running[r] = off; off += relCount[r]; }
    }
}

#define SCHUNK 2048
__global__ void scatter_kernel(const int* __restrict__ etype, int* __restrict__ bucket,
                               int* __restrict__ running, int nEdges) {
    __shared__ int cnt[NRELS];
    __shared__ int base[NRELS];
    int start = blockIdx.x * SCHUNK;
    int end = min(nEdges, start + SCHUNK);
    if (threadIdx.x < NRELS) cnt[threadIdx.x] = 0;
    __syncthreads();
    for (int i = start + threadIdx.x; i < end; i += blockDim.x)
        atomicAdd(&cnt[etype[i]], 1);
    __syncthreads();
    if (threadIdx.x < NRELS) {
        base[threadIdx.x] = atomicAdd(&running[threadIdx.x], cnt[threadIdx.x]);
        cnt[threadIdx.x] = 0;
    }
    __syncthreads();
    for (int i = start + threadIdx.x; i < end; i += blockDim.x) {
        int r = etype[i];
        int k = atomicAdd(&cnt[r], 1);
        bucket[base[r] + k] = i;
    }
}

// ---- per-edge transform + scatter-add. One wave per chunk of relation-sorted edges.
// W column held in VGPRs (reloaded only on relation change, rare after sort).
// x-row values are wave-uniform (one edge per wave-iteration) -> scalar operand FMAs.
template <int OUT>
__global__ void layer_kernel(const float* __restrict__ x, const float* __restrict__ W,
                             const int* __restrict__ bucket, const int* __restrict__ src,
                             const int* __restrict__ dst, const int* __restrict__ etype,
                             const float* __restrict__ norm, float* __restrict__ out,
                             int nEdges, int chunk) {
    const int lane = threadIdx.x & 63;
    const int wid = (blockIdx.x * blockDim.x + threadIdx.x) >> 6;
    int j0 = wid * chunk;
    if (j0 >= nEdges) return;
    int j1 = min(nEdges, j0 + chunk);

    constexpr int NW = (OUT == 64) ? 64 : 32;   // K-range per lane
    const int o = (OUT == 64) ? lane : (lane & 31);
    const int half = (OUT == 64) ? 0 : (lane >> 5);
    float w[NW];
    int cur_r = -1;

    for (int j = j0; j < j1; ++j) {
        int e = rfl(bucket[j]);
        int r = rfl(etype[e]);
        if (r != cur_r) {
            cur_r = r;
            const float* wp = W + (size_t)r * HD * OUT;
#pragma unroll
            for (int k = 0; k < NW; ++k) w[k] = wp[(half * NW + k) * OUT + o];
        }
        int s = rfl(src[e]);
        int d = rfl(dst[e]);
        float nm = rflf(norm[e]);
        const float* xp = x + (size_t)s * HD + half * NW;
        float acc = 0.f;
#pragma unroll
        for (int k = 0; k < NW; ++k) acc = fmaf(xp[k], w[k], acc);
        if (OUT == 64) {
            atomicAdd(&out[(size_t)d * 64 + lane], acc * nm);
        } else {
            acc += __shfl_xor(acc, 32);
            if (lane < 32) atomicAdd(&out[(size_t)d * 32 + o], acc * nm);
        }
    }
}

extern "C" void kernel_launch(void* const* d_in, const int* in_sizes, int n_in,
                              void* d_out, int out_size, void* d_ws, size_t ws_size,
                              hipStream_t stream) {
    const float* emb    = (const float*)d_in[0];
    const float* basis1 = (const float*)d_in[1];
    const float* comp1  = (const float*)d_in[2];
    const float* bias1  = (const float*)d_in[3];
    const float* basis2 = (const float*)d_in[4];
    const float* comp2  = (const float*)d_in[5];
    const float* bias2  = (const float*)d_in[6];
    const int*   src    = (const int*)d_in[7];
    const int*   dst    = (const int*)d_in[8];
    const int*   etype  = (const int*)d_in[9];
    const float* norm   = (const float*)d_in[10];
    float* out = (float*)d_out;

    const int nNodes = in_sizes[0] / HD;   // 200000
    const int nEdges = in_sizes[7];        // 1000000

    // workspace layout
    char* ws = (char*)d_ws;
    float* W1       = (float*)(ws);                    // 131072 B
    float* W2       = (float*)(ws + 131072);           // 65536 B
    int*   relCount = (int*)(ws + 196608);             // 32 B
    int*   running  = (int*)(ws + 196672);             // 32 B
    int*   bucket   = (int*)(ws + 262144);             // 4*nEdges B
    size_t h1_off = 262144 + (((size_t)nEdges * 4 + 4095) / 4096) * 4096;
    float* h1       = (float*)(ws + h1_off);           // 4*nNodes*64 B (~51.2 MB)

    hipMemsetAsync(ws + 196608, 0, 128, stream);

    wprep_kernel<<<(NRELS * HD * (HD + OD) + 255) / 256, 256, 0, stream>>>(
        basis1, comp1, basis2, comp2, W1, W2);
    init_kernel<<<4096, 256, 0, stream>>>(bias1, bias2, h1, out, nNodes);
    hist_kernel<<<1024, 256, 0, stream>>>(etype, relCount, nEdges);
    scan_kernel<<<1, 64, 0, stream>>>(relCount, running);
    scatter_kernel<<<(nEdges + SCHUNK - 1) / SCHUNK, 256, 0, stream>>>(
        etype, bucket, running, nEdges);

    const int nBlocks = 2048;                 // 8192 waves
    const int nWaves = nBlocks * (256 / 64);
    const int chunk = (nEdges + nWaves - 1) / nWaves;
    layer_kernel<64><<<nBlocks, 256, 0, stream>>>(emb, W1, bucket, src, dst, etype, norm,
                                                  h1, nEdges, chunk);
    layer_kernel<32><<<nBlocks, 256, 0, stream>>>(h1, W2, bucket, src, dst, etype, norm,
                                                  out, nEdges, chunk);
}

// Round 2
// 416.134 us; speedup vs baseline: 2.0557x; 2.0557x over previous
//
#include <hip/hip_runtime.h>

#define HD 64
#define NRELS 8
#define NB 8

// ---- precompute W1t[r][o][k] = sum_b comp1[r,b] basis1[b,k,o]  (transposed: k contiguous)
__global__ void wprep_kernel(const float* __restrict__ basis1, const float* __restrict__ comp1,
                             const float* __restrict__ basis2, const float* __restrict__ comp2,
                             float* __restrict__ W1t, float* __restrict__ W2t) {
    int idx = blockIdx.x * blockDim.x + threadIdx.x;
    const int n1 = NRELS * 64 * 64;   // 32768
    const int n2 = NRELS * 32 * 64;   // 16384
    if (idx < n1) {
        int r = idx >> 12, o = (idx >> 6) & 63, k = idx & 63;
        float s = 0.f;
#pragma unroll
        for (int b = 0; b < NB; ++b)
            s = fmaf(comp1[r * NB + b], basis1[b * 4096 + k * 64 + o], s);
        W1t[idx] = s;
    } else if (idx < n1 + n2) {
        int j = idx - n1;
        int r = j >> 11, o = (j >> 6) & 31, k = j & 63;
        float s = 0.f;
#pragma unroll
        for (int b = 0; b < NB; ++b)
            s = fmaf(comp2[r * NB + b], basis2[b * 2048 + k * 32 + o], s);
        W2t[j] = s;
    }
}

__global__ void init_kernel(const float* __restrict__ bias1, const float* __restrict__ bias2,
                            float* __restrict__ h1, float* __restrict__ out, int nNodes) {
    int n1 = nNodes * 64;
    int total = nNodes * (64 + 32);
    for (int idx = blockIdx.x * blockDim.x + threadIdx.x; idx < total;
         idx += gridDim.x * blockDim.x) {
        if (idx < n1) h1[idx] = bias1[idx & 63];
        else          out[idx - n1] = bias2[(idx - n1) & 31];
    }
}

__global__ void hist_kernel(const int* __restrict__ etype, int* __restrict__ relCount, int nEdges) {
    __shared__ int h[NRELS];
    if (threadIdx.x < NRELS) h[threadIdx.x] = 0;
    __syncthreads();
    for (int i = blockIdx.x * blockDim.x + threadIdx.x; i < nEdges;
         i += gridDim.x * blockDim.x)
        atomicAdd(&h[etype[i]], 1);
    __syncthreads();
    if (threadIdx.x < NRELS) atomicAdd(&relCount[threadIdx.x], h[threadIdx.x]);
}

__global__ void scan_kernel(const int* __restrict__ relCount, int* __restrict__ running) {
    if (threadIdx.x == 0 && blockIdx.x == 0) {
        int off = 0;
        for (int r = 0; r < NRELS; ++r) { running[r] = off; off += relCount[r]; }
    }
}

#define SCHUNK 2048
__global__ void scatter_kernel(const int* __restrict__ etype, int* __restrict__ bucket,
                               int* __restrict__ running, int nEdges) {
    __shared__ int cnt[NRELS];
    __shared__ int base[NRELS];
    int start = blockIdx.x * SCHUNK;
    int end = min(nEdges, start + SCHUNK);
    if (threadIdx.x < NRELS) cnt[threadIdx.x] = 0;
    __syncthreads();
    for (int i = start + threadIdx.x; i < end; i += blockDim.x)
        atomicAdd(&cnt[etype[i]], 1);
    __syncthreads();
    if (threadIdx.x < NRELS) {
        base[threadIdx.x] = atomicAdd(&running[threadIdx.x], cnt[threadIdx.x]);
        cnt[threadIdx.x] = 0;
    }
    __syncthreads();
    for (int i = start + threadIdx.x; i < end; i += blockDim.x) {
        int r = etype[i];
        int k = atomicAdd(&cnt[r], 1);
        bucket[base[r] + k] = i;
    }
}

// ---- edge layer: per-wave LDS double-buffered x-row staging + VGPR weights ----
// One wave owns CH=256 sorted edges (16 batches of 16). Per batch: stage 16 x-rows
// (256B each) into an 8KB wave-private LDS slab via global_load_lds, compute 16
// matvecs against W held in VGPRs (lane = output column), atomic-scatter to out.
// Counted vmcnt keeps the pipeline filled; asm markers pin memory-op order.
template <int OUT>
__global__ __launch_bounds__(256, 4) void layer_kernel(
    const float* __restrict__ x, const float* __restrict__ Wt,
    const int* __restrict__ bucket, const int* __restrict__ src,
    const int* __restrict__ dst, const int* __restrict__ etype,
    const float* __restrict__ norm, float* __restrict__ out, int nEdges) {
    constexpr int CH = 256;
    constexpr int NW = (OUT == 64) ? 64 : 32;
    __shared__ float lds[4 * 2 * 16 * 64];   // 4 waves x 2 slabs x 16 rows x 64f = 32KB
    const int lane = threadIdx.x & 63;
    const int wslot = threadIdx.x >> 6;
    const int wid = blockIdx.x * 4 + wslot;
    const int j0 = wid * CH;
    if (j0 >= nEdges) return;
    const int j1 = min(nEdges, j0 + CH);
    const int nB = (j1 - j0) >> 4;           // batches are always full (1e6 % 16 == 0)
    float* slab = &lds[wslot * 2048];

    const int o = (OUT == 64) ? lane : (lane & 31);
    const int koff = (OUT == 64) ? 0 : (lane >> 5) * 32;
    float w[NW];
    int cur_r = -1;

    auto stage = [&](int buf, int sv_) {
        float* lbase = slab + buf * 1024;
#pragma unroll
        for (int q = 0; q < 4; ++q) {
            int row = __shfl(sv_, q * 4 + (lane >> 4));
            const float* g = x + (size_t)row * HD + (lane & 15) * 4;
            __builtin_amdgcn_global_load_lds(
                (const __attribute__((address_space(1))) void*)g,
                (__attribute__((address_space(3))) void*)(lbase + q * 256), 16, 0, 0);
        }
    };

    auto compute8 = [&](int buf, int i0, int sv_, int dv_, int rv_, float nv_) {
        const float* base = slab + buf * 1024;
#pragma unroll
        for (int i = i0; i < i0 + 8; ++i) {
            int r = __builtin_amdgcn_readlane(rv_, i);
            if (r != cur_r) {
                cur_r = r;
                const float* wp = Wt + ((size_t)r * OUT + o) * HD + koff;
#pragma unroll
                for (int c = 0; c < NW / 4; ++c) {
                    float4 t = *reinterpret_cast<const float4*>(wp + c * 4);
                    w[c * 4 + 0] = t.x; w[c * 4 + 1] = t.y;
                    w[c * 4 + 2] = t.z; w[c * 4 + 3] = t.w;
                }
            }
            int d = __builtin_amdgcn_readlane(dv_, i);
            float nm = __uint_as_float(
                __builtin_amdgcn_readlane(__float_as_uint(nv_), i));
            const float* xr = base + i * 64 + koff;
            float acc = 0.f;
#pragma unroll
            for (int c = 0; c < NW / 4; ++c) {
                float4 xc = *reinterpret_cast<const float4*>(xr + c * 4);
                acc = fmaf(xc.x, w[c * 4 + 0], acc);
                acc = fmaf(xc.y, w[c * 4 + 1], acc);
                acc = fmaf(xc.z, w[c * 4 + 2], acc);
                acc = fmaf(xc.w, w[c * 4 + 3], acc);
            }
            acc *= nm;
            if (OUT == 64) {
                atomicAdd(out + (size_t)d * 64 + lane, acc);
            } else {
                acc += __shfl_xor(acc, 32);
                if (lane < 32) atomicAdd(out + (size_t)d * 32 + o, acc);
            }
        }
    };

    // prologue: meta(0), stage(0), bucket(1), full drain once
    int ml = lane & 15;
    int ev1 = bucket[j0 + ml];
    int sv = src[ev1], dv = dst[ev1], rv = etype[ev1];
    float nv = norm[ev1];
    stage(0, sv);
    ev1 = bucket[j0 + min(1, nB - 1) * 16 + ml];
    asm volatile("s_waitcnt vmcnt(0)" ::: "memory");

    for (int n = 0; n < nB; ++n) {
        const int cur = n & 1;
        // issue bucket(n+2) + meta(n+1) gathers : 5 VMEM
        int ev2 = bucket[j0 + min(n + 2, nB - 1) * 16 + ml];
        int sv2 = src[ev1], dv2 = dst[ev1], rv2 = etype[ev1];
        float nv2 = norm[ev1];
        // steady-state queue: [A(n-1)at:8][S(n):4][B(n-1)at:8][ev2:1][meta:4]
        // -> stage(n) complete once outstanding <= 13
        asm volatile("s_waitcnt vmcnt(13)" ::: "memory");
        compute8(cur, 0, sv, dv, rv, nv);          // 8 atomics
        asm volatile("" ::: "memory");
        if (n + 1 < nB) stage(cur ^ 1, sv2);       // 4 loads
        asm volatile("" ::: "memory");
        compute8(cur, 8, sv, dv, rv, nv);          // 8 atomics
        ev1 = ev2; sv = sv2; dv = dv2; rv = rv2; nv = nv2;
    }
}

extern "C" void kernel_launch(void* const* d_in, const int* in_sizes, int n_in,
                              void* d_out, int out_size, void* d_ws, size_t ws_size,
                              hipStream_t stream) {
    const float* emb    = (const float*)d_in[0];
    const float* basis1 = (const float*)d_in[1];
    const float* comp1  = (const float*)d_in[2];
    const float* bias1  = (const float*)d_in[3];
    const float* basis2 = (const float*)d_in[4];
    const float* comp2  = (const float*)d_in[5];
    const float* bias2  = (const float*)d_in[6];
    const int*   src    = (const int*)d_in[7];
    const int*   dst    = (const int*)d_in[8];
    const int*   etype  = (const int*)d_in[9];
    const float* norm   = (const float*)d_in[10];
    float* out = (float*)d_out;

    const int nNodes = in_sizes[0] / HD;   // 200000
    const int nEdges = in_sizes[7];        // 1000000

    char* ws = (char*)d_ws;
    float* W1t      = (float*)(ws);                    // 131072 B
    float* W2t      = (float*)(ws + 131072);           // 65536 B
    int*   relCount = (int*)(ws + 196608);
    int*   running  = (int*)(ws + 196672);
    int*   bucket   = (int*)(ws + 262144);             // 4 MB
    size_t h1_off = 262144 + (((size_t)nEdges * 4 + 4095) / 4096) * 4096;
    float* h1       = (float*)(ws + h1_off);           // 51.2 MB

    hipMemsetAsync(ws + 196608, 0, 128, stream);

    wprep_kernel<<<(NRELS * 64 * (64 + 32) + 255) / 256, 256, 0, stream>>>(
        basis1, comp1, basis2, comp2, W1t, W2t);
    init_kernel<<<4096, 256, 0, stream>>>(bias1, bias2, h1, out, nNodes);
    hist_kernel<<<1024, 256, 0, stream>>>(etype, relCount, nEdges);
    scan_kernel<<<1, 64, 0, stream>>>(relCount, running);
    scatter_kernel<<<(nEdges + SCHUNK - 1) / SCHUNK, 256, 0, stream>>>(
        etype, bucket, running, nEdges);

    const int nWaves = (nEdges + 255) / 256;           // 3907
    const int nBlocks = (nWaves + 3) / 4;              // 977
    layer_kernel<64><<<nBlocks, 256, 0, stream>>>(emb, W1t, bucket, src, dst, etype, norm,
                                                  h1, nEdges);
    layer_kernel<32><<<nBlocks, 256, 0, stream>>>(h1, W2t, bucket, src, dst, etype, norm,
                                                  out, nEdges);
}

// Round 3
// 374.579 us; speedup vs baseline: 2.2838x; 1.1109x over previous
//
#include <hip/hip_runtime.h>
#include <hip/hip_bf16.h>

#define NRELS 8
#define NB 8

typedef __attribute__((ext_vector_type(8))) short short8v;
typedef __attribute__((ext_vector_type(4))) float f32x4;

__device__ __forceinline__ short bfc(float f) {
    __hip_bfloat16 h = __float2bfloat16(f);
    return *reinterpret_cast<short*>(&h);
}
__device__ __forceinline__ short8v cvt8(float4 a, float4 b) {
    short8v r;
    r[0] = bfc(a.x); r[1] = bfc(a.y); r[2] = bfc(a.z); r[3] = bfc(a.w);
    r[4] = bfc(b.x); r[5] = bfc(b.y); r[6] = bfc(b.z); r[7] = bfc(b.w);
    return r;
}

// ---- precompute W in MFMA B-fragment order (bf16).
// Frag f = nt*2+ks of relation r: lane holds W[k = ks*32+(lane>>4)*8+j][n = nt*16+(lane&15)]
// Wf1: [8 rel][8 frags][64 lanes][8 bf16]; Wf2: [8 rel][4 frags][64][8]
__global__ void wprep_kernel(const float* __restrict__ basis1, const float* __restrict__ comp1,
                             const float* __restrict__ basis2, const float* __restrict__ comp2,
                             short* __restrict__ Wf1, short* __restrict__ Wf2) {
    int idx = blockIdx.x * blockDim.x + threadIdx.x;
    const int n1 = NRELS * 8 * 64 * 8;   // 32768
    const int n2 = NRELS * 4 * 64 * 8;   // 16384
    if (idx < n1) {
        int r = idx >> 12, f = (idx >> 9) & 7, lane = (idx >> 3) & 63, j = idx & 7;
        int k = (f & 1) * 32 + (lane >> 4) * 8 + j;
        int n = (f >> 1) * 16 + (lane & 15);
        float s = 0.f;
#pragma unroll
        for (int b = 0; b < NB; ++b)
            s = fmaf(comp1[r * NB + b], basis1[b * 4096 + k * 64 + n], s);
        Wf1[idx] = bfc(s);
    } else if (idx < n1 + n2) {
        int j2 = idx - n1;
        int r = j2 >> 11, f = (j2 >> 9) & 3, lane = (j2 >> 3) & 63, j = j2 & 7;
        int k = (f & 1) * 32 + (lane >> 4) * 8 + j;
        int n = (f >> 1) * 16 + (lane & 15);
        float s = 0.f;
#pragma unroll
        for (int b = 0; b < NB; ++b)
            s = fmaf(comp2[r * NB + b], basis2[b * 2048 + k * 32 + n], s);
        Wf2[j2] = bfc(s);
    }
}

__global__ void init_kernel(const float* __restrict__ bias1, const float* __restrict__ bias2,
                            float* __restrict__ h1, float* __restrict__ out, int nNodes) {
    int n1 = nNodes * 64;
    int total = nNodes * (64 + 32);
    for (int idx = blockIdx.x * blockDim.x + threadIdx.x; idx < total;
         idx += gridDim.x * blockDim.x) {
        if (idx < n1) h1[idx] = bias1[idx & 63];
        else          out[idx - n1] = bias2[(idx - n1) & 31];
    }
}

__global__ void hist_kernel(const int* __restrict__ etype, int* __restrict__ relCount, int nEdges) {
    __shared__ int h[NRELS];
    if (threadIdx.x < NRELS) h[threadIdx.x] = 0;
    __syncthreads();
    for (int i = blockIdx.x * blockDim.x + threadIdx.x; i < nEdges;
         i += gridDim.x * blockDim.x)
        atomicAdd(&h[etype[i]], 1);
    __syncthreads();
    if (threadIdx.x < NRELS) atomicAdd(&relCount[threadIdx.x], h[threadIdx.x]);
}

// paddedOff[r] = prefix of ceil(count/16)*16 ; paddedOff[8] = total padded edge count
__global__ void scan_kernel(const int* __restrict__ relCount, int* __restrict__ paddedOff,
                            int* __restrict__ running) {
    if (threadIdx.x == 0 && blockIdx.x == 0) {
        int off = 0;
        for (int r = 0; r < NRELS; ++r) {
            paddedOff[r] = off;
            running[r] = off;
            off += ((relCount[r] + 15) >> 4) << 4;
        }
        paddedOff[NRELS] = off;
    }
}

#define SCHUNK 2048
__global__ void scatter_kernel(const int* __restrict__ etype, const int* __restrict__ src,
                               const int* __restrict__ dst, const float* __restrict__ norm,
                               int* __restrict__ src_s, int* __restrict__ dst_s,
                               float* __restrict__ norm_s, int* __restrict__ running,
                               int nEdges) {
    __shared__ int cnt[NRELS];
    __shared__ int base[NRELS];
    int start = blockIdx.x * SCHUNK;
    int end = min(nEdges, start + SCHUNK);
    if (threadIdx.x < NRELS) cnt[threadIdx.x] = 0;
    __syncthreads();
    for (int i = start + threadIdx.x; i < end; i += blockDim.x)
        atomicAdd(&cnt[etype[i]], 1);
    __syncthreads();
    if (threadIdx.x < NRELS) {
        base[threadIdx.x] = atomicAdd(&running[threadIdx.x], cnt[threadIdx.x]);
        cnt[threadIdx.x] = 0;
    }
    __syncthreads();
    for (int i = start + threadIdx.x; i < end; i += blockDim.x) {
        int r = etype[i];
        int k = atomicAdd(&cnt[r], 1);
        int pos = base[r] + k;
        src_s[pos] = src[i];
        dst_s[pos] = dst[i];
        norm_s[pos] = norm[i];
    }
}

// ---- MFMA edge layer: one wave = one 16-edge tile (single relation after padding).
// A: gathered x rows, global->VGPR direct, bf16. B: pre-packed W frags from L2.
// D rows = edges -> shuffle dst/norm, atomic scatter. No LDS, no __syncthreads.
template <int OUT>
__global__ __launch_bounds__(256, 4) void layer_kernel(
    const float* __restrict__ x, const short* __restrict__ Wf,
    const int* __restrict__ src_s, const int* __restrict__ dst_s,
    const float* __restrict__ norm_s, const int* __restrict__ paddedOff,
    float* __restrict__ out, int T) {
    constexpr int NT = OUT / 16;
    constexpr int NF = NT * 2;
    const int lane = threadIdx.x & 63;
    const int wid = (blockIdx.x * blockDim.x + threadIdx.x) >> 6;
    const int ml = lane & 15;
    const int kg = lane >> 4;

    int offv = (lane < 9) ? paddedOff[lane] : 0x7fffffff;
    const int nTiles = __shfl(offv, 8) >> 4;
    const int t0 = wid * T;
    const int t1 = min(t0 + T, nTiles);
    if (t0 >= t1) return;

    // meta for tile t0 (lanes 0..15 own edges; 16..63 duplicate)
    int e = (t0 << 4) + ml;
    int sv = src_s[e], dv = dst_s[e];
    float nv = norm_s[e];
    // raw A rows for t0
    const float* xp = x + (size_t)sv * 64 + kg * 8;
    float4 a0 = *(const float4*)xp;
    float4 a1 = *(const float4*)(xp + 4);
    float4 a2 = *(const float4*)(xp + 32);
    float4 a3 = *(const float4*)(xp + 36);
    // meta for tile t0+1
    int sv2 = 0, dv2 = 0; float nv2 = 0.f;
    if (t0 + 1 < t1) {
        int e2 = ((t0 + 1) << 4) + ml;
        sv2 = src_s[e2]; dv2 = dst_s[e2]; nv2 = norm_s[e2];
    }

    short8v B[NT][2];
    int cur_r = -1;

    for (int t = t0; t < t1; ++t) {
        // relation of this tile: count padded offsets <= first edge index
        unsigned long long bl = __ballot(lane < 8 && offv <= (t << 4));
        int r = __builtin_amdgcn_readfirstlane(__popcll(bl) - 1);
        if (r != cur_r) {
            cur_r = r;
            const short* wp = Wf + (((size_t)r * NF) * 64 + lane) * 8;
#pragma unroll
            for (int nt = 0; nt < NT; ++nt)
#pragma unroll
                for (int ks = 0; ks < 2; ++ks)
                    B[nt][ks] = *(const short8v*)(wp + (nt * 2 + ks) * 64 * 8);
        }
        // convert raw A -> fragments (waits on this tile's x loads)
        short8v A0 = cvt8(a0, a1);
        short8v A1 = cvt8(a2, a3);
        // prefetch next tile's A rows
        if (t + 1 < t1) {
            const float* xq = x + (size_t)sv2 * 64 + kg * 8;
            a0 = *(const float4*)xq;
            a1 = *(const float4*)(xq + 4);
            a2 = *(const float4*)(xq + 32);
            a3 = *(const float4*)(xq + 36);
        }
        // 16x16x32 MFMAs: D[row=edge][col=out]
        f32x4 acc[NT];
#pragma unroll
        for (int nt = 0; nt < NT; ++nt) {
            acc[nt] = __builtin_amdgcn_mfma_f32_16x16x32_bf16(A0, B[nt][0],
                                                              (f32x4){0.f, 0.f, 0.f, 0.f}, 0, 0, 0);
            acc[nt] = __builtin_amdgcn_mfma_f32_16x16x32_bf16(A1, B[nt][1], acc[nt], 0, 0, 0);
        }
        // epilogue: row = kg*4 + i, col = nt*16 + ml
#pragma unroll
        for (int i = 0; i < 4; ++i) {
            int row = kg * 4 + i;
            int d = __shfl(dv, row);
            float nm = __shfl(nv, row);
            float* ob = out + (size_t)d * OUT + ml;
#pragma unroll
            for (int nt = 0; nt < NT; ++nt)
                atomicAdd(ob + nt * 16, acc[nt][i] * nm);
        }
        // rotate meta pipeline
        sv = sv2; dv = dv2; nv = nv2;
        if (t + 2 < t1) {
            int e3 = ((t + 2) << 4) + ml;
            sv2 = src_s[e3]; dv2 = dst_s[e3]; nv2 = norm_s[e3];
        }
    }
}

extern "C" void kernel_launch(void* const* d_in, const int* in_sizes, int n_in,
                              void* d_out, int out_size, void* d_ws, size_t ws_size,
                              hipStream_t stream) {
    const float* emb    = (const float*)d_in[0];
    const float* basis1 = (const float*)d_in[1];
    const float* comp1  = (const float*)d_in[2];
    const float* bias1  = (const float*)d_in[3];
    const float* basis2 = (const float*)d_in[4];
    const float* comp2  = (const float*)d_in[5];
    const float* bias2  = (const float*)d_in[6];
    const int*   src    = (const int*)d_in[7];
    const int*   dst    = (const int*)d_in[8];
    const int*   etype  = (const int*)d_in[9];
    const float* norm   = (const float*)d_in[10];
    float* out = (float*)d_out;

    const int nNodes = in_sizes[0] / 64;   // 200000
    const int nEdges = in_sizes[7];        // 1000000

    // padded edge capacity (each of 8 segments padded to x16), rounded to x64 ints
    const int padStride = ((nEdges + NRELS * 16 + 63) / 64) * 64;

    char* ws = (char*)d_ws;
    short* Wf1      = (short*)(ws);                         // 65536 B
    short* Wf2      = (short*)(ws + 65536);                 // 32768 B
    int*   relCount = (int*)(ws + 98304);                   // 8 ints
    int*   paddedOff= (int*)(ws + 98304 + 32);              // 9 ints
    int*   running  = (int*)(ws + 98304 + 96);              // 8 ints
    int*   src_s    = (int*)(ws + 131072);
    int*   dst_s    = (int*)(ws + 131072 + (size_t)padStride * 4);
    float* norm_s   = (float*)(ws + 131072 + (size_t)padStride * 8);
    float* h1       = (float*)(ws + 131072 + (size_t)padStride * 12);  // 256B-aligned

    hipMemsetAsync(ws + 98304, 0, 256, stream);
    hipMemsetAsync(ws + 131072, 0, (size_t)padStride * 12, stream);  // zero sorted meta (padding -> norm 0)

    wprep_kernel<<<(NRELS * 64 * (64 + 32) + 255) / 256, 256, 0, stream>>>(
        basis1, comp1, basis2, comp2, Wf1, Wf2);
    init_kernel<<<4096, 256, 0, stream>>>(bias1, bias2, h1, out, nNodes);
    hist_kernel<<<1024, 256, 0, stream>>>(etype, relCount, nEdges);
    scan_kernel<<<1, 64, 0, stream>>>(relCount, paddedOff, running);
    scatter_kernel<<<(nEdges + SCHUNK - 1) / SCHUNK, 256, 0, stream>>>(
        etype, src, dst, norm, src_s, dst_s, norm_s, running, nEdges);

    const int tilesMax = (nEdges + NRELS * 16) / 16;   // >= device nTiles
    const int nBlocks = 2048;
    const int nWaves = nBlocks * 4;
    const int T = (tilesMax + nWaves - 1) / nWaves;
    layer_kernel<64><<<nBlocks, 256, 0, stream>>>(emb, Wf1, src_s, dst_s, norm_s,
                                                  paddedOff, h1, T);
    layer_kernel<32><<<nBlocks, 256, 0, stream>>>(h1, Wf2, src_s, dst_s, norm_s,
                                                  paddedOff, out, T);
}